// Round 9
// baseline (174.623 us; speedup 1.0000x reference)
//
#include <hip/hip_runtime.h>
#include <math.h>

#define VOCAB 1024
#define ED 64
#define NROWS 65536            // 64*32*32 flattened rows
#define NELEM 4194304          // 64*64*32*32
#define MARGIN 2.0e-4f         // validated R3/R4 (passed, absmax 0)
#define CAPF 8192              // flagged-row slots (expect ~2500-4200)

typedef __attribute__((ext_vector_type(8))) short short8;
typedef __attribute__((ext_vector_type(4))) float f32x4;

__device__ __forceinline__ unsigned f2bf(float f) {
    unsigned u = __float_as_uint(f);
    u += 0x7fff + ((u >> 16) & 1);   // RNE to bf16
    return u >> 16;
}

// pack (distance, code) into a sortable u64 key: min(key) == lex-min (d, c)
__device__ __forceinline__ unsigned long long packkey(float d, int c) {
    unsigned f = __float_as_uint(d);
    unsigned sd = (f & 0x80000000u) ? ~f : (f | 0x80000000u);
    return ((unsigned long long)sd << 32) | (unsigned)c;
}

// ws layout:
//   [0,       4096)    float e2f[1024]       fl32(fp64 ||e||^2)  (R2-proven)
//   [4096,    4100)    unsigned nflag
//   [4100,    4112)    pad
//   [4112,    8208)    unsigned hist[1024]
//   [8208,    40976)   unsigned rowlist[CAPF]
//   [40976,   172048)  uint4 FB[8192]        bf16 MFMA-B fragments (128 KB)
//   [172048,  174096)  double lossp[256]     per-merge-block loss partials
//   [174096,  178192)  double lossp2[512]    per-rescue-block loss partials
//   [178192,  1226768) float pb1[4][65536]   per-chunk best1
//   [1226768, 2275344) float pb2[4][65536]   per-chunk best2
//   [2275344, 2799632) ushort pi1[4][65536]  per-chunk best index
//   [2799632, 4896784) float zrow[CAPF*64]   compact z rows of flagged slots (2 MB)
//
// FB fragment layout (identical bits to round-0 stage_chunk):
//   entry i: n=i&15, q=(i>>4)&3, kh=(i>>6)&1, T=i>>7
//   holds bf16x8 of emb[T*16+n][kh*32+q*8 .. +8)
//   scan reads bf[kh] = ((short8*)FB)[T*128 + kh*64 + lane], lane=q*16+n_lo

// ---------------- prep: e2f + bf16 fragment table + workspace zeroing ----------------
__global__ void vq_prep(const float* __restrict__ emb, float* __restrict__ e2f,
                        uint4* __restrict__ FB, unsigned* __restrict__ zw1,
                        unsigned* __restrict__ zw2) {
    const int tid = blockIdx.x * 256 + threadIdx.x;   // 0..2047
    // zero nflag+pad+hist (1028 words) and lossp+lossp2 (1536 words)
    for (int i = tid; i < 1028; i += 2048) zw1[i] = 0u;
    for (int i = tid; i < 1536; i += 2048) zw2[i] = 0u;

    if (tid < VOCAB) {
        const float4* src = (const float4*)(emb + tid * ED);
        double s = 0.0;
        #pragma unroll
        for (int g = 0; g < 16; ++g) {
            float4 f = src[g];
            s = fma((double)f.x, (double)f.x, s);
            s = fma((double)f.y, (double)f.y, s);
            s = fma((double)f.z, (double)f.z, s);
            s = fma((double)f.w, (double)f.w, s);
        }
        e2f[tid] = (float)s;
    }
    #pragma unroll
    for (int e = 0; e < 4; ++e) {
        const int i = e * 2048 + tid;                 // 0..8191
        const int n = i & 15, q = (i >> 4) & 3, kh = (i >> 6) & 1, T = i >> 7;
        const int code = T * 16 + n;
        const int k0 = kh * 32 + q * 8;
        const float4* sp = (const float4*)(emb + code * 64 + k0);
        float4 f0 = sp[0], f1 = sp[1];
        uint4 pk;
        pk.x = f2bf(f0.x) | (f2bf(f0.y) << 16);
        pk.y = f2bf(f0.z) | (f2bf(f0.w) << 16);
        pk.z = f2bf(f1.x) | (f2bf(f1.y) << 16);
        pk.w = f2bf(f1.z) | (f2bf(f1.w) << 16);
        FB[i] = pk;
    }
}

// ---------------- scan: 2048 blocks = 512 row-groups x 4 code-chunks ----------------
// Block (rg, ck): 128 rows, 256 codes (16 T-tiles). Pure MFMA scan + per-row partial
// top-2 write. No barriers in loop, no epilogue. Math bit-identical to validated R8.
__global__ __launch_bounds__(256, 4)
void vq_scan(const float* __restrict__ z, const float* __restrict__ e2f,
             const uint4* __restrict__ FB, float* __restrict__ pb1,
             float* __restrict__ pb2, unsigned short* __restrict__ pi1) {
    __shared__ float e2s[256];

    const int t = threadIdx.x;
    const int w = t >> 6, lane = t & 63;
    const int q = lane >> 4, n_lo = lane & 15;
    const int bk = blockIdx.x;
    const int rg = bk >> 2, ck = bk & 3;
    const int n0 = rg * 128;
    const int b  = n0 >> 10;
    const int sb = n0 & 1023;

    if (t < 256) e2s[t] = e2f[ck * 256 + t];

    // A fragments: bf16(-2 z) for this wave's 32 rows (bit-identical values per row)
    short8 af[2][2];
    #pragma unroll
    for (int rt = 0; rt < 2; ++rt) {
        const int s = sb + w * 32 + rt * 16 + n_lo;
        const float* zp = z + (size_t)b * 65536 + s;
        #pragma unroll
        for (int kh = 0; kh < 2; ++kh) {
            short8 fr;
            #pragma unroll
            for (int j = 0; j < 8; ++j) {
                int d = kh * 32 + q * 8 + j;
                fr[j] = (short)f2bf(-2.0f * zp[d * 1024]);
            }
            af[rt][kh] = fr;
        }
    }

    float b1[8], b2[8]; int i1[8];
    #pragma unroll
    for (int sl = 0; sl < 8; ++sl) { b1[sl] = 3.4e38f; b2[sl] = 3.4e38f; i1[sl] = 0; }

    __syncthreads();                     // e2s ready

    // ---- MFMA scan over this block's 16 T-tiles, B-fragments straight from global ----
    const short8* FBs = (const short8*)FB;
    #pragma unroll 4
    for (int tt = 0; tt < 16; ++tt) {
        const int T = ck * 16 + tt;
        short8 bf0 = FBs[T * 128 + lane];          // kh=0
        short8 bf1 = FBs[T * 128 + 64 + lane];     // kh=1
        const int cb = T * 16 + n_lo;
        const float e2 = e2s[tt * 16 + n_lo];
        #pragma unroll
        for (int rt = 0; rt < 2; ++rt) {
            f32x4 a; a[0] = e2; a[1] = e2; a[2] = e2; a[3] = e2;
            a = __builtin_amdgcn_mfma_f32_16x16x32_bf16(af[rt][0], bf0, a, 0, 0, 0);
            a = __builtin_amdgcn_mfma_f32_16x16x32_bf16(af[rt][1], bf1, a, 0, 0, 0);
            #pragma unroll
            for (int reg = 0; reg < 4; ++reg) {
                const int sl = rt * 4 + reg;
                float s0 = a[reg];
                b2[sl] = __builtin_amdgcn_fmed3f(s0, b1[sl], b2[sl]);
                bool lt = s0 < b1[sl];
                i1[sl] = lt ? cb : i1[sl];
                b1[sl] = lt ? s0 : b1[sl];
            }
        }
    }

    // merge across the 16 code-lanes of each quad (identical to validated logic)
    #pragma unroll
    for (int m = 1; m < 16; m <<= 1) {
        #pragma unroll
        for (int sl = 0; sl < 8; ++sl) {
            float ob1 = __shfl_xor(b1[sl], m, 64);
            int   oi1 = __shfl_xor(i1[sl], m, 64);
            float ob2 = __shfl_xor(b2[sl], m, 64);
            float lose = fmaxf(b1[sl], ob1);
            b2[sl] = fminf(fminf(b2[sl], ob2), lose);
            bool take = (ob1 < b1[sl]) || (ob1 == b1[sl] && oi1 < i1[sl]);
            b1[sl] = take ? ob1 : b1[sl];
            i1[sl] = take ? oi1 : i1[sl];
        }
    }
    if (n_lo == 0) {
        #pragma unroll
        for (int rt = 0; rt < 2; ++rt) {
            #pragma unroll
            for (int reg = 0; reg < 4; ++reg) {
                const int sl = rt * 4 + reg;
                const int gr = ck * 65536 + n0 + w * 32 + rt * 16 + q * 4 + reg;
                pb1[gr] = b1[sl];
                pb2[gr] = b2[sl];
                pi1[gr] = (unsigned short)i1[sl];
            }
        }
    }
}

// ---------------- merge: row-per-thread. Chunk-merge (validated formula) + flag +
// index/hist + coalesced z_q_st epilogue + zrow dump + per-block loss partial ----------
__global__ __launch_bounds__(256, 2)
void vq_merge(const float* __restrict__ z, const float* __restrict__ emb,
              const float* __restrict__ pb1, const float* __restrict__ pb2,
              const unsigned short* __restrict__ pi1, float* __restrict__ out,
              double* __restrict__ lossp, unsigned* __restrict__ hist,
              unsigned* __restrict__ nflag, unsigned* __restrict__ rowlist,
              float* __restrict__ zrow) {
    __shared__ unsigned wcnt[4], wpf[4], bshare;
    __shared__ double wls[4];

    const int t = threadIdx.x, w = t >> 6, lane = t & 63;
    const int nrow = blockIdx.x * 256 + t;            // 256 blocks x 256 rows
    const int b = nrow >> 10, s = nrow & 1023;

    // sequential chunk merge, ascending chunk order == sequential code order.
    // strict < keeps earlier chunk's index on value ties (first-occurrence);
    // b2 via the validated lose-formula == sequential second-best.
    float B1 = pb1[nrow], B2 = pb2[nrow]; int I1 = (int)pi1[nrow];
    #pragma unroll
    for (int c = 1; c < 4; ++c) {
        const float c1 = pb1[c * 65536 + nrow];
        const float c2 = pb2[c * 65536 + nrow];
        const int   ci = (int)pi1[c * 65536 + nrow];
        const float lose = fmaxf(B1, c1);
        B2 = fminf(fminf(B2, c2), lose);
        if (c1 < B1) { B1 = c1; I1 = ci; }
    }

    // flag: block-aggregated reservation (ONE atomic per block)
    const bool want = B2 < B1 + MARGIN;
    const unsigned long long mask = __ballot(want);
    const int cnt = __popcll(mask);
    if (lane == 0) wcnt[w] = (unsigned)cnt;
    __syncthreads();
    if (t == 0) {
        const unsigned p0 = wcnt[0], p1 = wcnt[1], p2 = wcnt[2], p3 = wcnt[3];
        const unsigned tot = p0 + p1 + p2 + p3;
        bshare = tot ? atomicAdd(nflag, tot) : 0u;
        wpf[0] = 0; wpf[1] = p0; wpf[2] = p0 + p1; wpf[3] = p0 + p1 + p2;
    }
    __syncthreads();
    int myslot = -1;
    if (want) {
        const int rank = __popcll(mask & ((1ULL << lane) - 1ULL));
        const unsigned slot = bshare + wpf[w] + (unsigned)rank;
        if (slot < CAPF) { rowlist[slot] = (unsigned)nrow; myslot = (int)slot; }
        // overflow (slot>=CAPF): treated unflagged, same as validated kernel
    }
    out[NELEM + nrow] = (float)I1;       // rescue overwrites if flagged
    if (myslot < 0) atomicAdd(&hist[I1], 1u);

    // epilogue: coalesced z_q_st + loss (fp64 partials, 2 chains); zrow dump if flagged
    double l0 = 0.0, l1 = 0.0;
    const float4* em4 = (const float4*)(emb + I1 * 64);
    #pragma unroll
    for (int d4 = 0; d4 < 16; ++d4) {
        const float4 e4 = em4[d4];       // gather, L2-hot
        const float es[4] = {e4.x, e4.y, e4.z, e4.w};
        #pragma unroll
        for (int j = 0; j < 4; ++j) {
            const int d = d4 * 4 + j;
            const size_t off = (size_t)b * 65536 + (size_t)d * 1024 + s;
            const float zv = z[off];                 // coalesced 1KB/wave... per d
            out[off] = zv + (es[j] - zv);            // coalesced
            if (myslot >= 0) zrow[(size_t)myslot * 64 + d] = zv;
            const double df = (double)es[j] - (double)zv;
            if (j & 1) l1 = fma(df, df, l1); else l0 = fma(df, df, l0);
        }
    }
    double lsum = (myslot >= 0) ? 0.0 : (l0 + l1);   // rescue adds flagged rows' loss
    #pragma unroll
    for (int o = 32; o > 0; o >>= 1) lsum += __shfl_down(lsum, o, 64);
    if (lane == 0) wls[w] = lsum;
    __syncthreads();
    if (t == 0) lossp[blockIdx.x] = wls[0] + wls[1] + wls[2] + wls[3];   // NO atomic
}

// ---------------- rescue: UNCHANGED R8 (validated). 512 blocks x 16 slots;
// lane<->code (e in regs), z from compact zrow ----------------
#define EDOT(i) { \
    const float4 a4 = za4[i]; \
    const float4 b4 = zb4[i]; \
    ma = fmaf(a4.x, e##i[0], ma); ma = fmaf(a4.y, e##i[1], ma); \
    ma = fmaf(a4.z, e##i[2], ma); ma = fmaf(a4.w, e##i[3], ma); \
    mb = fmaf(b4.x, e##i[0], mb); mb = fmaf(b4.y, e##i[1], mb); \
    mb = fmaf(b4.z, e##i[2], mb); mb = fmaf(b4.w, e##i[3], mb); }

__global__ __launch_bounds__(512, 1)
void vq_rescue(const float* __restrict__ zrow, const float* __restrict__ emb,
               const float* __restrict__ e2f, float* __restrict__ out,
               double* __restrict__ lossp2, unsigned* __restrict__ hist,
               const unsigned* __restrict__ nflag,
               const unsigned* __restrict__ rowlist) {
    __shared__ float zns[16];
    __shared__ unsigned long long wkey[16][16];   // [pass*8+w][row]
    __shared__ int rbi[16];
    __shared__ double lred[8];

    const int t = threadIdx.x, w = t >> 6, lane = t & 63;
    const int g = blockIdx.x;            // 512 blocks, 16 slots each
    unsigned nfr = *nflag;
    const int nf = (int)(nfr < CAPF ? nfr : CAPF);
    if (g * 16 >= nf) return;
    const int nloc = (nf - g * 16 < 16) ? (nf - g * 16) : 16;

    // zn per row: fl32(fp64 sequential ||z||^2) from contiguous zrow (R2-proven chain)
    if (t < nloc) {
        const float* zp = zrow + (size_t)(g * 16 + t) * 64;
        double a = 0.0;
        for (int k = 0; k < 64; ++k) { const double v = (double)zp[k]; a = fma(v, v, a); }
        zns[t] = (float)a;
    }
    __syncthreads();

    // two passes of 512 codes; rows two-at-a-time (2 independent fmaf chains)
    for (int pass = 0; pass < 2; ++pass) {
        const int cbase = pass * 512 + w * 64;
        const int c = cbase + lane;
        const f32x4* ep = (const f32x4*)(emb + (size_t)c * 64);
        f32x4 e0 = ep[0],  e1 = ep[1],  e2 = ep[2],  e3 = ep[3];
        f32x4 e4 = ep[4],  e5 = ep[5],  e6 = ep[6],  e7 = ep[7];
        f32x4 e8 = ep[8],  e9 = ep[9],  e10 = ep[10], e11 = ep[11];
        f32x4 e12 = ep[12], e13 = ep[13], e14 = ep[14], e15 = ep[15];
        const float e2c = e2f[c];

        for (int r0 = 0; r0 < nloc; r0 += 2) {
            const bool two = (r0 + 1 < nloc);
            const float4* za4 = (const float4*)(zrow + (size_t)(g * 16 + r0) * 64);
            const float4* zb4 = (const float4*)(zrow + (size_t)(g * 16 + (two ? r0 + 1 : r0)) * 64);
            float ma = 0.f, mb = 0.f;
            EDOT(0)  EDOT(1)  EDOT(2)  EDOT(3)
            EDOT(4)  EDOT(5)  EDOT(6)  EDOT(7)
            EDOT(8)  EDOT(9)  EDOT(10) EDOT(11)
            EDOT(12) EDOT(13) EDOT(14) EDOT(15)

            {   // wave argmin: fmin reduce + ballot; lowest lane = lowest code (exact tie-break)
                const float da = (zns[r0] + e2c) - 2.0f * ma;   // exact validated form
                float dmin = da;
                #pragma unroll
                for (int mo = 32; mo > 0; mo >>= 1)
                    dmin = fminf(dmin, __shfl_xor(dmin, mo, 64));
                const unsigned long long ball = __ballot(da == dmin);
                const int wl = __ffsll(ball) - 1;
                if (lane == 0) wkey[pass * 8 + w][r0] = packkey(dmin, cbase + wl);
            }
            if (two) {
                const float db = (zns[r0 + 1] + e2c) - 2.0f * mb;
                float dmin = db;
                #pragma unroll
                for (int mo = 32; mo > 0; mo >>= 1)
                    dmin = fminf(dmin, __shfl_xor(dmin, mo, 64));
                const unsigned long long ball = __ballot(db == dmin);
                const int wl = __ffsll(ball) - 1;
                if (lane == 0) wkey[pass * 8 + w][r0 + 1] = packkey(dmin, cbase + wl);
            }
        }
    }
    __syncthreads();

    // per-row merge of 16 wave-candidates (lex-min key = first-occurrence)
    if (t < nloc) {
        unsigned long long k0 = wkey[0][t];
        #pragma unroll
        for (int i = 1; i < 16; ++i) {
            unsigned long long ki = wkey[i][t];
            if (ki < k0) k0 = ki;
        }
        const int code = (int)(unsigned)(k0 & 0xffffffffu);
        rbi[t] = code;
        const int row = (int)rowlist[g * 16 + t];
        out[NELEM + row] = (float)code;
        atomicAdd(&hist[code], 1u);      // distributed addresses
    }
    __syncthreads();

    // outputs + loss: 8 threads per row, 8 dims each; z from compact zrow (coalesced)
    double lsum = 0.0;
    if (t < 128) {
        const int r = t >> 3, d0 = (t & 7) * 8;
        if (r < nloc) {
            const int row = (int)rowlist[g * 16 + r];
            const int bb = row >> 10, s = row & 1023;
            const int code = rbi[r];
            float4 ea = *(const float4*)(emb + code * 64 + d0);
            float4 eb = *(const float4*)(emb + code * 64 + d0 + 4);
            float es[8] = {ea.x, ea.y, ea.z, ea.w, eb.x, eb.y, eb.z, eb.w};
            const float* zp = zrow + (size_t)(g * 16 + r) * 64 + d0;
            #pragma unroll
            for (int j = 0; j < 8; ++j) {
                const int d = d0 + j;
                const size_t off = (size_t)bb * 65536 + (size_t)d * 1024 + s;
                const float zv = zp[j];
                out[off] = zv + (es[j] - zv);
                double df = (double)es[j] - (double)zv;
                lsum = fma(df, df, lsum);
            }
        }
    }
    #pragma unroll
    for (int o = 32; o > 0; o >>= 1) lsum += __shfl_down(lsum, o, 64);
    if (lane == 0) lred[w] = lsum;
    __syncthreads();
    if (t == 0) {
        double s = 0.0;
        #pragma unroll
        for (int i = 0; i < 8; ++i) s += lred[i];
        lossp2[g] = s;                   // NO atomic (zeroed in prep)
    }
}

// ---------------- finalize: sum loss partials + entropy ----------------
__global__ void vq_finalize_kernel(const unsigned* __restrict__ hist,
                                   const double* __restrict__ lossp,
                                   const double* __restrict__ lossp2,
                                   float* __restrict__ out) {
    __shared__ double red[256], red2[256];
    int t = threadIdx.x;
    double ssum = 0.0, lsum = 0.0;
    for (int i = t; i < VOCAB; i += 256) {
        double p = (double)hist[i] / (double)NROWS;
        ssum += p * log(p + 1e-10);
    }
    lsum += lossp[t];                    // 256 merge partials
    for (int i = t; i < 512; i += 256) lsum += lossp2[i];
    red[t] = ssum; red2[t] = lsum;
    __syncthreads();
    for (int off = 128; off > 0; off >>= 1) {
        if (t < off) { red[t] += red[t + off]; red2[t] += red2[t + off]; }
        __syncthreads();
    }
    if (t == 0) {
        double qv = red2[0] / (double)NELEM;
        out[NELEM + NROWS + 0] = (float)qv;
        out[NELEM + NROWS + 1] = (float)(qv * 0.25);
        out[NELEM + NROWS + 2] = (float)exp(-red[0]);
    }
}

extern "C" void kernel_launch(void* const* d_in, const int* in_sizes, int n_in,
                              void* d_out, int out_size, void* d_ws, size_t ws_size,
                              hipStream_t stream) {
    const float* z   = (const float*)d_in[0];   // (64,64,32,32) fp32
    const float* emb = (const float*)d_in[1];   // (1024,64) fp32
    float* out = (float*)d_out;

    float*          e2f     = (float*)d_ws;
    unsigned*       nfl     = (unsigned*)((char*)d_ws + 4096);
    unsigned*       hist    = (unsigned*)((char*)d_ws + 4112);
    unsigned*       rowlist = (unsigned*)((char*)d_ws + 8208);
    uint4*          FB      = (uint4*)((char*)d_ws + 40976);
    double*         lossp   = (double*)((char*)d_ws + 172048);
    double*         lossp2  = (double*)((char*)d_ws + 174096);
    float*          pb1     = (float*)((char*)d_ws + 178192);
    float*          pb2     = (float*)((char*)d_ws + 1226768);
    unsigned short* pi1     = (unsigned short*)((char*)d_ws + 2275344);
    float*          zrow    = (float*)((char*)d_ws + 2799632);
    unsigned*       zw1     = (unsigned*)((char*)d_ws + 4096);    // nflag+pad+hist (1028 words)
    unsigned*       zw2     = (unsigned*)((char*)d_ws + 172048);  // lossp+lossp2 (1536 words)

    vq_prep<<<dim3(8), dim3(256), 0, stream>>>(emb, e2f, FB, zw1, zw2);
    vq_scan<<<dim3(2048), dim3(256), 0, stream>>>(z, e2f, FB, pb1, pb2, pi1);
    vq_merge<<<dim3(256), dim3(256), 0, stream>>>(z, emb, pb1, pb2, pi1, out,
                                                  lossp, hist, nfl, rowlist, zrow);
    vq_rescue<<<dim3(512), dim3(512), 0, stream>>>(zrow, emb, e2f, out, lossp2,
                                                   hist, nfl, rowlist);
    vq_finalize_kernel<<<dim3(1), dim3(256), 0, stream>>>(hist, lossp, lossp2, out);
}